// Round 3
// baseline (693.457 us; speedup 1.0000x reference)
//
#include <hip/hip_runtime.h>

// ---------------------------------------------------------------------------
// In2MA: windowed dual attention. B=4, C=64, H=W=256, WIN=8, HEADS=8, INNER=64
// 4096 windows of 64 tokens x 64 ch. One 512-thread block per window.
// R5: R3's __launch_bounds__(512,4) was interpreted as 4 BLOCKS/CU ->
// VGPR capped at 64 -> lrow[64] spilled to scratch (hbm_bytes 0.31->1.73 GB,
// dur 365->600us). Fix: amdgpu_waves_per_eu(4) (unambiguous LLVM attr) ->
// VGPR cap 512/4 = 128, which this per-wave code fit in at R2 with no spill.
// LDS 78848 B independently caps at 2 blocks/CU = 16 waves/CU = 4 waves/SIMD.
// fp32 activations in LDS + split-bf16 MFMA, strides padded to x4 floats.
// ---------------------------------------------------------------------------

typedef __attribute__((ext_vector_type(8))) short short8;   // 8 bf16 (4 VGPRs)
typedef __attribute__((ext_vector_type(4))) float floatx4;  // MFMA accum

#define CCH  64
#define HH   256
#define WWD  256
#define HWsz (HH*WWD)
#define CHW  (CCH*HH*WWD)

// weight plane element offsets (hi plane at [0,WTOT), lo plane at [WTOT,2*WTOT))
#define OWPQ  0      // W_pan_q    32x32
#define OWPK  1024   // W_pan_k    32x32
#define OWV1  2048   // W_v1       64x64
#define OWV2  6144   // W_v2       64x64
#define OWK2  10240  // W_k2       32x64
#define OWQ1C 12288  // W_q1c      32x64
#define OWK1C 14336  // W_k1c      32x64
#define OWIO  16384  // W_inner_out 64x64
#define OWINT 20480  // W_inter_out 64x64
#define WTOT  24576

__device__ __forceinline__ unsigned int f2bf_u(float f) {   // RNE, value in low 16
    unsigned int u = __builtin_bit_cast(unsigned int, f);
    u += 0x7FFFu + ((u >> 16) & 1u);
    return u >> 16;
}
__device__ __forceinline__ float bfu2f(unsigned int b) {
    return __builtin_bit_cast(float, b << 16);
}

union Frag { short8 v; unsigned int u[4]; };
template <int KS> struct AF { Frag ah[KS], al[KS]; };

// Load + split-convert the A fragments for rows [m0,m0+16), K wide.
// MFMA 16x16x32_bf16 A layout: lane holds A[m=lane&15][k=quad*8+j].
template <int K, int SA>
__device__ __forceinline__ AF<K / 32> load_afrag(const float* __restrict__ A,
                                                 int m0, int lane) {
    AF<K / 32> f;
    const int l15 = lane & 15;
    const int quad = lane >> 4;
#pragma unroll
    for (int kk = 0; kk < K / 32; ++kk) {
        const float4* ap = (const float4*)(A + (m0 + l15) * SA + kk * 32 + quad * 8);
        float4 fa = ap[0], fb = ap[1];
        float ff[8] = {fa.x, fa.y, fa.z, fa.w, fb.x, fb.y, fb.z, fb.w};
#pragma unroll
        for (int j2 = 0; j2 < 4; ++j2) {
            float f0 = ff[2 * j2], f1 = ff[2 * j2 + 1];
            unsigned int h0 = f2bf_u(f0), h1 = f2bf_u(f1);
            float r0 = f0 - bfu2f(h0), r1 = f1 - bfu2f(h1);
            f.ah[kk].u[j2] = h0 | (h1 << 16);
            f.al[kk].u[j2] = f2bf_u(r0) | (f2bf_u(r1) << 16);
        }
    }
    return f;
}

// O rows [m0,m0+16), cols [n0, n0+16*NT) = A(16xK) @ W(NxK)^T with split-bf16
// fp32 emulation: Ah@Wh + Al@Wh + Ah@Wl (drop Al@Wl ~2^-18).
// D layout: lane holds D[row=quad*4+r][col=lane&15].
template <int K, int SO, int NT>
__device__ __forceinline__ void mm(const AF<K / 32>& f,
                                   const unsigned short* __restrict__ Wh,
                                   const unsigned short* __restrict__ Wl,
                                   float* __restrict__ O,
                                   int m0, int n0, int lane) {
    const int l15 = lane & 15;
    const int quad = lane >> 4;
#pragma unroll
    for (int nt = 0; nt < NT; ++nt) {
        floatx4 acc = {0.f, 0.f, 0.f, 0.f};
#pragma unroll
        for (int kk = 0; kk < K / 32; ++kk) {
            const int wo = (n0 + nt * 16 + l15) * K + kk * 32 + quad * 8;
            short8 bh = *(const short8*)(Wh + wo);
            short8 bl = *(const short8*)(Wl + wo);
            acc = __builtin_amdgcn_mfma_f32_16x16x32_bf16(f.ah[kk].v, bh, acc, 0, 0, 0);
            acc = __builtin_amdgcn_mfma_f32_16x16x32_bf16(f.al[kk].v, bh, acc, 0, 0, 0);
            acc = __builtin_amdgcn_mfma_f32_16x16x32_bf16(f.ah[kk].v, bl, acc, 0, 0, 0);
        }
#pragma unroll
        for (int r = 0; r < 4; ++r)
            O[(m0 + quad * 4 + r) * SO + n0 + nt * 16 + l15] = acc[r];
    }
}

// ---------------------------------------------------------------------------
// Weight fp32 -> bf16 hi/lo planes (once per launch; ws re-poisoned each call)
// ---------------------------------------------------------------------------
__global__ void cvt_w(const float* __restrict__ w0, const float* __restrict__ w1,
                      const float* __restrict__ w2, const float* __restrict__ w3,
                      const float* __restrict__ w4, const float* __restrict__ w5,
                      const float* __restrict__ w6, const float* __restrict__ w7,
                      const float* __restrict__ w8, unsigned short* __restrict__ o) {
    int i = blockIdx.x * 256 + threadIdx.x;
    const float* src; int off;
    if      (i < 1024)  { src = w0; off = 0; }
    else if (i < 2048)  { src = w1; off = 1024; }
    else if (i < 6144)  { src = w2; off = 2048; }
    else if (i < 10240) { src = w3; off = 6144; }
    else if (i < 12288) { src = w4; off = 10240; }
    else if (i < 14336) { src = w5; off = 12288; }
    else if (i < 16384) { src = w6; off = 14336; }
    else if (i < 20480) { src = w7; off = 16384; }
    else                { src = w8; off = 20480; }
    float f = src[i - off];
    unsigned int h = f2bf_u(f);
    o[i] = (unsigned short)h;
    o[WTOT + i] = (unsigned short)f2bf_u(f - bfu2f(h));
}

// ---------------------------------------------------------------------------
// Main fused kernel: one 512-thread block per window. LDS (fp32, stride in fl):
//  s_xf (68): xf (phA) -> out1 (phC)                         17408 B
//  s_cat(68): pan cols0-31 + q1c cols32-63 -> cat -> out2    17408 B
//  s_v1 (68): v1 -> x_v2 -> final                            17408 B
//  s_qk (68): pan_q cols0-31, pan_k cols32-63                17408 B
//  s_k2 (36): k1c -> x_k2                                     9216 B
// total 78848 B -> 2 blocks/CU = 16 waves/CU. waves_per_eu(4) -> VGPR cap 128.
// ---------------------------------------------------------------------------
__global__ __attribute__((amdgpu_flat_work_group_size(512, 512),
                          amdgpu_waves_per_eu(4)))
void in2ma_main(
    const float* __restrict__ x, const float* __restrict__ pan,
    const float* __restrict__ posi, const float* __restrict__ posc,
    const unsigned short* __restrict__ wb, float* __restrict__ out) {
    __shared__ __align__(16) float s_xf[64 * 68];
    __shared__ __align__(16) float s_cat[64 * 68];
    __shared__ __align__(16) float s_v1[64 * 68];
    __shared__ __align__(16) float s_qk[64 * 68];
    __shared__ __align__(16) float s_k2[64 * 36];

    const int tid  = threadIdx.x;
    const int wave = tid >> 6;   // 0..7
    const int lane = tid & 63;
    const int wid  = blockIdx.x;
    const int b    = wid >> 10;
    const int hn_i = (wid >> 5) & 31;
    const int wn_i = wid & 31;
    const int h0 = hn_i * 8, w0 = wn_i * 8;

    const float scale = 0.35355339059327373f;  // 8^-0.5 (both attentions)
    const unsigned short* wlo = wb + WTOT;

    // ---- S0: stage x window -> s_xf, pan window -> s_cat cols 0-31 (fp32) ----
    // x: thread = (row hl=wave, channel c=lane). LDS write banks (4*wl+c)%32:
    // 2-way max (free). pan on waves 0-3: (hl2 = 2w+(lane>>5), c2 = lane&31).
    {
        const int c = lane, hl = wave;
        const float* xp = x + (size_t)b * CHW + (size_t)c * HWsz
                            + (size_t)(h0 + hl) * WWD + w0;
        const float4* p = (const float4*)xp;
        float4 a = p[0], q = p[1];
        float* d = s_xf + (hl * 8) * 68 + c;
        d[0 * 68] = a.x; d[1 * 68] = a.y; d[2 * 68] = a.z; d[3 * 68] = a.w;
        d[4 * 68] = q.x; d[5 * 68] = q.y; d[6 * 68] = q.z; d[7 * 68] = q.w;
        if (wave < 4) {
            const int hl2 = wave * 2 + (lane >> 5);
            const int c2 = lane & 31;
            const float* pp = pan + (size_t)b * (CHW / 2) + (size_t)c2 * HWsz
                                  + (size_t)(h0 + hl2) * WWD + w0;
            const float4* p2 = (const float4*)pp;
            float4 a2 = p2[0], q2 = p2[1];
            float* d2 = s_cat + (hl2 * 8) * 68 + c2;
            d2[0 * 68] = a2.x; d2[1 * 68] = a2.y; d2[2 * 68] = a2.z; d2[3 * 68] = a2.w;
            d2[4 * 68] = q2.x; d2[5 * 68] = q2.y; d2[6 * 68] = q2.z; d2[7 * 68] = q2.w;
        }
    }
    __syncthreads();

    // ---- Phase A: 5 projections over 8 waves (balanced ~30 MFMA/wave).
    // All outputs/inputs disjoint -> no intra-phase barrier.
    if (wave < 4) {
        AF<2> f = load_afrag<64, 68>(s_xf, wave * 16, lane);
        mm<64, 68, 4>(f, wb + OWV1, wlo + OWV1, s_v1, wave * 16, 0, lane);   // x_v1
        AF<1> g = load_afrag<32, 68>(s_cat, wave * 16, lane);
        mm<32, 68, 2>(g, wb + OWPQ, wlo + OWPQ, s_qk, wave * 16, 0, lane);   // pan_q
    } else {
        const int s = wave - 4;
        AF<2> f = load_afrag<64, 68>(s_xf, s * 16, lane);                    // shared conv
        mm<64, 68, 2>(f, wb + OWQ1C, wlo + OWQ1C, s_cat + 32, s * 16, 0, lane); // q1c
        mm<64, 36, 2>(f, wb + OWK1C, wlo + OWK1C, s_k2, s * 16, 0, lane);    // k1c
        AF<1> g = load_afrag<32, 68>(s_cat, s * 16, lane);
        mm<32, 68, 2>(g, wb + OWPK, wlo + OWPK, s_qk + 32, s * 16, 0, lane); // pan_k
    }
    __syncthreads();

    // ---- S3: pan MHA (8 heads, d=4, seq=64). wave = head, lane = token. ----
    {
        const int h = wave;
        const float4 qv = *(const float4*)(s_qk + lane * 68 + 4 * h);   // 16B aligned
        const float q0 = qv.x, q1 = qv.y, q2 = qv.z, q3 = qv.w;
        const float4* pp4 = (const float4*)(posi + h * 4096 + lane * 64);
        float lrow[64];
        float sden = 0.f;
#pragma unroll
        for (int t4 = 0; t4 < 16; ++t4) {
            float4 pv = pp4[t4];
            float pvv[4] = {pv.x, pv.y, pv.z, pv.w};
#pragma unroll
            for (int u = 0; u < 4; ++u) {
                const int t = t4 * 4 + u;
                const float4 kv = *(const float4*)(s_qk + t * 68 + 32 + 4 * h); // bcast b128
                float d = q0 * kv.x + q1 * kv.y + q2 * kv.z + q3 * kv.w;
                float e = __expf(d * scale + pvv[u]);
                lrow[t] = e; sden += e;
            }
        }
        const float inv = 1.f / sden;
        float o0 = 0.f, o1 = 0.f, o2 = 0.f, o3 = 0.f;
#pragma unroll
        for (int t = 0; t < 64; ++t) {
            const float4 vv = *(const float4*)(s_v1 + t * 68 + 4 * h);  // bcast b128
            float p = lrow[t];
            o0 += p * vv.x; o1 += p * vv.y; o2 += p * vv.z; o3 += p * vv.w;
        }
        float4 ov; ov.x = o0 * inv; ov.y = o1 * inv; ov.z = o2 * inv; ov.w = o3 * inv;
        *(float4*)(s_cat + lane * 68 + 4 * h) = ov;  // cat cols [0,32)
    }

    // ---- S5: color MHA (seq=32 channels, d=8 token-dims) on waves 0-3.
    // wave w: heads 2w (lanes 0-31), 2w+1 (lanes 32-63). Head h touches only
    // rows 16w..16w+15 == own wave's strip; reads (cat cols 32-63, k2,
    // v1 cols 32-63) all barrier-covered from Phase A -> no barrier after S3.
    if (wave < 4) {
        const int h = wave * 2 + (lane >> 5);
        const int i = lane & 31;
        float q[8];
#pragma unroll
        for (int j = 0; j < 8; ++j) q[j] = s_cat[(8 * h + j) * 68 + 32 + i];  // q1c
        float lr[32];
#pragma unroll
        for (int j = 0; j < 8; ++j) {
            const float* kp = s_k2 + (8 * h + j) * 36;  // k1c row, broadcast
            const float qj = q[j];
#pragma unroll
            for (int t = 0; t < 32; ++t) {
                float kv = kp[t];
                if (j == 0) lr[t] = qj * kv; else lr[t] += qj * kv;
            }
        }
        const float4* pp4 = (const float4*)(posc + h * 1024 + i * 32);
        float sden = 0.f;
#pragma unroll
        for (int t4 = 0; t4 < 8; ++t4) {
            float4 pv = pp4[t4];
            float pvv[4] = {pv.x, pv.y, pv.z, pv.w};
#pragma unroll
            for (int u = 0; u < 4; ++u) {
                const int t = t4 * 4 + u;
                float e = __expf(lr[t] * scale + pvv[u]);
                lr[t] = e; sden += e;
            }
        }
        const float inv = 1.f / sden;
#pragma unroll
        for (int j = 0; j < 8; ++j) {
            const float* vp = s_v1 + (8 * h + j) * 68 + 32;  // v1_color
            float acc = 0.f;
#pragma unroll
            for (int t = 0; t < 32; ++t) acc += lr[t] * vp[t];
            s_cat[(8 * h + j) * 68 + 32 + i] = acc * inv;  // cat cols [32,64)
        }
    }
    __syncthreads();

    // ---- Phase C: out1 = cat@Wio^T ; x_v2 = out1@Wv2^T ; x_k2 = out1@Wk2^T.
    // Waves w and w+4 redundantly compute the SAME out1 strip (bit-identical
    // MFMA -> benign duplicate stores) so the chain stays strip-local: no
    // extra barrier needed before x_v2 / x_k2.
    {
        const int s = wave & 3;
        AF<2> f = load_afrag<64, 68>(s_cat, s * 16, lane);
        mm<64, 68, 4>(f, wb + OWIO, wlo + OWIO, s_xf, s * 16, 0, lane);      // out1
        AF<2> g = load_afrag<64, 68>(s_xf, s * 16, lane);                    // own strip
        if (wave < 4)
            mm<64, 68, 4>(g, wb + OWV2, wlo + OWV2, s_v1, s * 16, 0, lane);  // x_v2
        else
            mm<64, 36, 2>(g, wb + OWK2, wlo + OWK2, s_k2, s * 16, 0, lane);  // x_k2
    }
    __syncthreads();

    // ---- S8: inter attention (cosine gate). wave = head, lane = token. ----
    {
        const int t = lane, h = wave;
        const float4 qv = *(const float4*)(s_qk + t * 68 + 4 * h);   // pan_q
        const float4 kv = *(const float4*)(s_k2 + t * 36 + 4 * h);   // x_k2
        float qq = qv.x * qv.x + qv.y * qv.y + qv.z * qv.z + qv.w * qv.w;
        float kk = kv.x * kv.x + kv.y * kv.y + kv.z * kv.z + kv.w * kv.w;
        float qk = qv.x * kv.x + qv.y * kv.y + qv.z * kv.z + qv.w * kv.w;
        float cosv = qk * rsqrtf(qq * kk);
        const float4* vp = (const float4*)(s_v1 + t * 68 + 8 * h);   // x_v2
        float4* op = (float4*)(s_cat + t * 68 + 8 * h);              // out2
        float4 v0 = vp[0], v1 = vp[1];
        float4 r0, r1;
        r0.x = cosv * v0.x; r0.y = cosv * v0.y; r0.z = cosv * v0.z; r0.w = cosv * v0.w;
        r1.x = cosv * v1.x; r1.y = cosv * v1.y; r1.z = cosv * v1.z; r1.w = cosv * v1.w;
        op[0] = r0; op[1] = r1;
    }
    __syncthreads();

    // ---- S9: final = out2 @ Wint^T -> s_v1 (8 half-strip tasks) ----
    {
        AF<2> f = load_afrag<64, 68>(s_cat, (wave >> 1) * 16, lane);
        mm<64, 68, 2>(f, wb + OWINT, wlo + OWINT, s_v1,
                      (wave >> 1) * 16, (wave & 1) * 32, lane);
    }
    __syncthreads();

    // ---- store: LDS transpose -> coalesced fp32 float4 stores.
    // thread = (row hl=wave, channel c=lane); LDS read banks (4*wl+c)%32: 2-way.
    {
        const int c = lane, hl = wave;
        float* op = out + (size_t)b * CHW + (size_t)c * HWsz
                        + (size_t)(h0 + hl) * WWD + w0;
        float v[8];
#pragma unroll
        for (int wl = 0; wl < 8; ++wl)
            v[wl] = s_v1[(hl * 8 + wl) * 68 + c];
        float4 q0; q0.x = v[0]; q0.y = v[1]; q0.z = v[2]; q0.w = v[3];
        float4 q1; q1.x = v[4]; q1.y = v[5]; q1.z = v[6]; q1.w = v[7];
        float4* q = (float4*)op;
        q[0] = q0; q[1] = q1;
    }
}

extern "C" void kernel_launch(void* const* d_in, const int* in_sizes, int n_in,
                              void* d_out, int out_size, void* d_ws, size_t ws_size,
                              hipStream_t stream) {
    (void)in_sizes; (void)n_in; (void)out_size; (void)ws_size;
    const float* x    = (const float*)d_in[0];
    const float* pan  = (const float*)d_in[1];
    const float* posi = (const float*)d_in[11];
    const float* posc = (const float*)d_in[12];
    unsigned short* wb = (unsigned short*)d_ws;  // 2*WTOT*2 = 98304 B of ws

    cvt_w<<<WTOT / 256, 256, 0, stream>>>(
        (const float*)d_in[2], (const float*)d_in[3], (const float*)d_in[4],
        (const float*)d_in[5], (const float*)d_in[6], (const float*)d_in[7],
        (const float*)d_in[8], (const float*)d_in[9], (const float*)d_in[10], wb);

    in2ma_main<<<4096, 512, 0, stream>>>(x, pan, posi, posc, wb, (float*)d_out);
}

// Round 4
// 577.840 us; speedup vs baseline: 1.2001x; 1.2001x over previous
//
#include <hip/hip_runtime.h>

// ---------------------------------------------------------------------------
// In2MA: windowed dual attention. B=4, C=64, H=W=256, WIN=8, HEADS=8, INNER=64
// 4096 windows of 64 tokens x 64 ch. One 512-thread block per window.
// R6: both (512,4) launch_bounds and amdgpu_waves_per_eu(4) left the VGPR
// budget at 64 -> lrow[64]/lr[32] spilled (hbm 0.31->1.73 GB). Fix: make the
// kernel spill-free AT 64 VGPRs: S3 and S5 softmax become two-pass
// (denominator pass + recompute-exp accumulate pass), peak live ~30 regs.
// LDS 78848 B -> 2 blocks/CU = 16 waves/CU = 4 waves/EU, now without spills.
// fp32 activations in LDS + split-bf16 MFMA, strides padded to x4 floats.
// ---------------------------------------------------------------------------

typedef __attribute__((ext_vector_type(8))) short short8;   // 8 bf16 (4 VGPRs)
typedef __attribute__((ext_vector_type(4))) float floatx4;  // MFMA accum

#define CCH  64
#define HH   256
#define WWD  256
#define HWsz (HH*WWD)
#define CHW  (CCH*HH*WWD)

// weight plane element offsets (hi plane at [0,WTOT), lo plane at [WTOT,2*WTOT))
#define OWPQ  0      // W_pan_q    32x32
#define OWPK  1024   // W_pan_k    32x32
#define OWV1  2048   // W_v1       64x64
#define OWV2  6144   // W_v2       64x64
#define OWK2  10240  // W_k2       32x64
#define OWQ1C 12288  // W_q1c      32x64
#define OWK1C 14336  // W_k1c      32x64
#define OWIO  16384  // W_inner_out 64x64
#define OWINT 20480  // W_inter_out 64x64
#define WTOT  24576

__device__ __forceinline__ unsigned int f2bf_u(float f) {   // RNE, value in low 16
    unsigned int u = __builtin_bit_cast(unsigned int, f);
    u += 0x7FFFu + ((u >> 16) & 1u);
    return u >> 16;
}
__device__ __forceinline__ float bfu2f(unsigned int b) {
    return __builtin_bit_cast(float, b << 16);
}

union Frag { short8 v; unsigned int u[4]; };
template <int KS> struct AF { Frag ah[KS], al[KS]; };

// Load + split-convert the A fragments for rows [m0,m0+16), K wide.
// MFMA 16x16x32_bf16 A layout: lane holds A[m=lane&15][k=quad*8+j].
template <int K, int SA>
__device__ __forceinline__ AF<K / 32> load_afrag(const float* __restrict__ A,
                                                 int m0, int lane) {
    AF<K / 32> f;
    const int l15 = lane & 15;
    const int quad = lane >> 4;
#pragma unroll
    for (int kk = 0; kk < K / 32; ++kk) {
        const float4* ap = (const float4*)(A + (m0 + l15) * SA + kk * 32 + quad * 8);
        float4 fa = ap[0], fb = ap[1];
        float ff[8] = {fa.x, fa.y, fa.z, fa.w, fb.x, fb.y, fb.z, fb.w};
#pragma unroll
        for (int j2 = 0; j2 < 4; ++j2) {
            float f0 = ff[2 * j2], f1 = ff[2 * j2 + 1];
            unsigned int h0 = f2bf_u(f0), h1 = f2bf_u(f1);
            float r0 = f0 - bfu2f(h0), r1 = f1 - bfu2f(h1);
            f.ah[kk].u[j2] = h0 | (h1 << 16);
            f.al[kk].u[j2] = f2bf_u(r0) | (f2bf_u(r1) << 16);
        }
    }
    return f;
}

// O rows [m0,m0+16), cols [n0, n0+16*NT) = A(16xK) @ W(NxK)^T with split-bf16
// fp32 emulation: Ah@Wh + Al@Wh + Ah@Wl (drop Al@Wl ~2^-18).
// D layout: lane holds D[row=quad*4+r][col=lane&15].
template <int K, int SO, int NT>
__device__ __forceinline__ void mm(const AF<K / 32>& f,
                                   const unsigned short* __restrict__ Wh,
                                   const unsigned short* __restrict__ Wl,
                                   float* __restrict__ O,
                                   int m0, int n0, int lane) {
    const int l15 = lane & 15;
    const int quad = lane >> 4;
#pragma unroll
    for (int nt = 0; nt < NT; ++nt) {
        floatx4 acc = {0.f, 0.f, 0.f, 0.f};
#pragma unroll
        for (int kk = 0; kk < K / 32; ++kk) {
            const int wo = (n0 + nt * 16 + l15) * K + kk * 32 + quad * 8;
            short8 bh = *(const short8*)(Wh + wo);
            short8 bl = *(const short8*)(Wl + wo);
            acc = __builtin_amdgcn_mfma_f32_16x16x32_bf16(f.ah[kk].v, bh, acc, 0, 0, 0);
            acc = __builtin_amdgcn_mfma_f32_16x16x32_bf16(f.al[kk].v, bh, acc, 0, 0, 0);
            acc = __builtin_amdgcn_mfma_f32_16x16x32_bf16(f.ah[kk].v, bl, acc, 0, 0, 0);
        }
#pragma unroll
        for (int r = 0; r < 4; ++r)
            O[(m0 + quad * 4 + r) * SO + n0 + nt * 16 + l15] = acc[r];
    }
}

// ---------------------------------------------------------------------------
// Weight fp32 -> bf16 hi/lo planes (once per launch; ws re-poisoned each call)
// ---------------------------------------------------------------------------
__global__ void cvt_w(const float* __restrict__ w0, const float* __restrict__ w1,
                      const float* __restrict__ w2, const float* __restrict__ w3,
                      const float* __restrict__ w4, const float* __restrict__ w5,
                      const float* __restrict__ w6, const float* __restrict__ w7,
                      const float* __restrict__ w8, unsigned short* __restrict__ o) {
    int i = blockIdx.x * 256 + threadIdx.x;
    const float* src; int off;
    if      (i < 1024)  { src = w0; off = 0; }
    else if (i < 2048)  { src = w1; off = 1024; }
    else if (i < 6144)  { src = w2; off = 2048; }
    else if (i < 10240) { src = w3; off = 6144; }
    else if (i < 12288) { src = w4; off = 10240; }
    else if (i < 14336) { src = w5; off = 12288; }
    else if (i < 16384) { src = w6; off = 14336; }
    else if (i < 20480) { src = w7; off = 16384; }
    else                { src = w8; off = 20480; }
    float f = src[i - off];
    unsigned int h = f2bf_u(f);
    o[i] = (unsigned short)h;
    o[WTOT + i] = (unsigned short)f2bf_u(f - bfu2f(h));
}

// ---------------------------------------------------------------------------
// Main fused kernel: one 512-thread block per window. LDS (fp32, stride in fl):
//  s_xf (68): xf (phA) -> out1 (phC)                         17408 B
//  s_cat(68): pan cols0-31 + q1c cols32-63 -> cat -> out2    17408 B
//  s_v1 (68): v1 -> x_v2 -> final                            17408 B
//  s_qk (68): pan_q cols0-31, pan_k cols32-63                17408 B
//  s_k2 (36): k1c -> x_k2                                     9216 B
// total 78848 B -> 2 blocks/CU = 16 waves/CU. Code is spill-free at 64 VGPR.
// ---------------------------------------------------------------------------
__global__ __attribute__((amdgpu_flat_work_group_size(512, 512)))
void in2ma_main(
    const float* __restrict__ x, const float* __restrict__ pan,
    const float* __restrict__ posi, const float* __restrict__ posc,
    const unsigned short* __restrict__ wb, float* __restrict__ out) {
    __shared__ __align__(16) float s_xf[64 * 68];
    __shared__ __align__(16) float s_cat[64 * 68];
    __shared__ __align__(16) float s_v1[64 * 68];
    __shared__ __align__(16) float s_qk[64 * 68];
    __shared__ __align__(16) float s_k2[64 * 36];

    const int tid  = threadIdx.x;
    const int wave = tid >> 6;   // 0..7
    const int lane = tid & 63;
    const int wid  = blockIdx.x;
    const int b    = wid >> 10;
    const int hn_i = (wid >> 5) & 31;
    const int wn_i = wid & 31;
    const int h0 = hn_i * 8, w0 = wn_i * 8;

    const float scale = 0.35355339059327373f;  // 8^-0.5 (both attentions)
    const unsigned short* wlo = wb + WTOT;

    // ---- S0: stage x window -> s_xf, pan window -> s_cat cols 0-31 (fp32) ----
    // x: thread = (row hl=wave, channel c=lane). LDS write banks (4*wl+c)%32:
    // 2-way max (free). pan on waves 0-3: (hl2 = 2w+(lane>>5), c2 = lane&31).
    {
        const int c = lane, hl = wave;
        const float* xp = x + (size_t)b * CHW + (size_t)c * HWsz
                            + (size_t)(h0 + hl) * WWD + w0;
        const float4* p = (const float4*)xp;
        float4 a = p[0], q = p[1];
        float* d = s_xf + (hl * 8) * 68 + c;
        d[0 * 68] = a.x; d[1 * 68] = a.y; d[2 * 68] = a.z; d[3 * 68] = a.w;
        d[4 * 68] = q.x; d[5 * 68] = q.y; d[6 * 68] = q.z; d[7 * 68] = q.w;
        if (wave < 4) {
            const int hl2 = wave * 2 + (lane >> 5);
            const int c2 = lane & 31;
            const float* pp = pan + (size_t)b * (CHW / 2) + (size_t)c2 * HWsz
                                  + (size_t)(h0 + hl2) * WWD + w0;
            const float4* p2 = (const float4*)pp;
            float4 a2 = p2[0], q2 = p2[1];
            float* d2 = s_cat + (hl2 * 8) * 68 + c2;
            d2[0 * 68] = a2.x; d2[1 * 68] = a2.y; d2[2 * 68] = a2.z; d2[3 * 68] = a2.w;
            d2[4 * 68] = q2.x; d2[5 * 68] = q2.y; d2[6 * 68] = q2.z; d2[7 * 68] = q2.w;
        }
    }
    __syncthreads();

    // ---- Phase A: 5 projections over 8 waves (balanced ~30 MFMA/wave).
    // All outputs/inputs disjoint -> no intra-phase barrier.
    if (wave < 4) {
        AF<2> f = load_afrag<64, 68>(s_xf, wave * 16, lane);
        mm<64, 68, 4>(f, wb + OWV1, wlo + OWV1, s_v1, wave * 16, 0, lane);   // x_v1
        AF<1> g = load_afrag<32, 68>(s_cat, wave * 16, lane);
        mm<32, 68, 2>(g, wb + OWPQ, wlo + OWPQ, s_qk, wave * 16, 0, lane);   // pan_q
    } else {
        const int s = wave - 4;
        AF<2> f = load_afrag<64, 68>(s_xf, s * 16, lane);                    // shared conv
        mm<64, 68, 2>(f, wb + OWQ1C, wlo + OWQ1C, s_cat + 32, s * 16, 0, lane); // q1c
        mm<64, 36, 2>(f, wb + OWK1C, wlo + OWK1C, s_k2, s * 16, 0, lane);    // k1c
        AF<1> g = load_afrag<32, 68>(s_cat, s * 16, lane);
        mm<32, 68, 2>(g, wb + OWPK, wlo + OWPK, s_qk + 32, s * 16, 0, lane); // pan_k
    }
    __syncthreads();

    // ---- S3: pan MHA (8 heads, d=4, seq=64). wave = head, lane = token.
    // Two-pass softmax (no lrow[64] array -> spill-free at 64 VGPR):
    // pass 1 accumulates the denominator, pass 2 recomputes exp (bit-identical
    // inputs -> bit-identical e) and accumulates the output. pos re-read is
    // L1-hot (16KB/wave just touched).
    {
        const int h = wave;
        const float4 qv = *(const float4*)(s_qk + lane * 68 + 4 * h);   // 16B aligned
        const float q0 = qv.x, q1 = qv.y, q2 = qv.z, q3 = qv.w;
        const float4* pp4 = (const float4*)(posi + h * 4096 + lane * 64);
        float sden = 0.f;
#pragma unroll
        for (int t4 = 0; t4 < 16; ++t4) {
            float4 pv = pp4[t4];
            float pvv[4] = {pv.x, pv.y, pv.z, pv.w};
#pragma unroll
            for (int u = 0; u < 4; ++u) {
                const int t = t4 * 4 + u;
                const float4 kv = *(const float4*)(s_qk + t * 68 + 32 + 4 * h); // bcast b128
                float d = q0 * kv.x + q1 * kv.y + q2 * kv.z + q3 * kv.w;
                sden += __expf(d * scale + pvv[u]);
            }
        }
        const float inv = 1.f / sden;
        float o0 = 0.f, o1 = 0.f, o2 = 0.f, o3 = 0.f;
#pragma unroll
        for (int t4 = 0; t4 < 16; ++t4) {
            float4 pv = pp4[t4];
            float pvv[4] = {pv.x, pv.y, pv.z, pv.w};
#pragma unroll
            for (int u = 0; u < 4; ++u) {
                const int t = t4 * 4 + u;
                const float4 kv = *(const float4*)(s_qk + t * 68 + 32 + 4 * h); // bcast b128
                float d = q0 * kv.x + q1 * kv.y + q2 * kv.z + q3 * kv.w;
                float e = __expf(d * scale + pvv[u]);
                const float4 vv = *(const float4*)(s_v1 + t * 68 + 4 * h);      // bcast b128
                o0 += e * vv.x; o1 += e * vv.y; o2 += e * vv.z; o3 += e * vv.w;
            }
        }
        float4 ov; ov.x = o0 * inv; ov.y = o1 * inv; ov.z = o2 * inv; ov.w = o3 * inv;
        *(float4*)(s_cat + lane * 68 + 4 * h) = ov;  // cat cols [0,32)
    }

    // ---- S5: color MHA (seq=32 channels, d=8 token-dims) on waves 0-3.
    // wave w: heads 2w (lanes 0-31), 2w+1 (lanes 32-63). Two-pass softmax
    // (no lr[32] array): peak live = q[8]+acc[8]+misc ~30 VGPR.
    // Reads (cat cols 32-63, k2, v1 cols 32-63) barrier-covered from Phase A.
    if (wave < 4) {
        const int h = wave * 2 + (lane >> 5);
        const int i = lane & 31;
        float q[8];
#pragma unroll
        for (int j = 0; j < 8; ++j) q[j] = s_cat[(8 * h + j) * 68 + 32 + i];  // q1c
        const float4* pp4 = (const float4*)(posc + h * 1024 + i * 32);
        float sden = 0.f;
#pragma unroll
        for (int t4 = 0; t4 < 8; ++t4) {
            float4 pv = pp4[t4];
            float pvv[4] = {pv.x, pv.y, pv.z, pv.w};
#pragma unroll
            for (int u = 0; u < 4; ++u) {
                const int t = t4 * 4 + u;
                float sc = 0.f;
#pragma unroll
                for (int j = 0; j < 8; ++j)
                    sc += q[j] * s_k2[(8 * h + j) * 36 + t];   // k1c, bcast
                sden += __expf(sc * scale + pvv[u]);
            }
        }
        const float inv = 1.f / sden;
        float acc[8] = {0.f, 0.f, 0.f, 0.f, 0.f, 0.f, 0.f, 0.f};
#pragma unroll
        for (int t4 = 0; t4 < 8; ++t4) {
            float4 pv = pp4[t4];
            float pvv[4] = {pv.x, pv.y, pv.z, pv.w};
#pragma unroll
            for (int u = 0; u < 4; ++u) {
                const int t = t4 * 4 + u;
                float sc = 0.f;
#pragma unroll
                for (int j = 0; j < 8; ++j)
                    sc += q[j] * s_k2[(8 * h + j) * 36 + t];   // k1c, bcast
                float e = __expf(sc * scale + pvv[u]);
#pragma unroll
                for (int j = 0; j < 8; ++j)
                    acc[j] += e * s_v1[(8 * h + j) * 68 + 32 + t];  // v1_color, bcast
            }
        }
#pragma unroll
        for (int j = 0; j < 8; ++j)
            s_cat[(8 * h + j) * 68 + 32 + i] = acc[j] * inv;  // cat cols [32,64)
    }
    __syncthreads();

    // ---- Phase C: out1 = cat@Wio^T ; x_v2 = out1@Wv2^T ; x_k2 = out1@Wk2^T.
    // Waves w and w+4 redundantly compute the SAME out1 strip (bit-identical
    // MFMA -> benign duplicate stores) so the chain stays strip-local: no
    // extra barrier needed before x_v2 / x_k2.
    {
        const int s = wave & 3;
        AF<2> f = load_afrag<64, 68>(s_cat, s * 16, lane);
        mm<64, 68, 4>(f, wb + OWIO, wlo + OWIO, s_xf, s * 16, 0, lane);      // out1
        AF<2> g = load_afrag<64, 68>(s_xf, s * 16, lane);                    // own strip
        if (wave < 4)
            mm<64, 68, 4>(g, wb + OWV2, wlo + OWV2, s_v1, s * 16, 0, lane);  // x_v2
        else
            mm<64, 36, 2>(g, wb + OWK2, wlo + OWK2, s_k2, s * 16, 0, lane);  // x_k2
    }
    __syncthreads();

    // ---- S8: inter attention (cosine gate). wave = head, lane = token. ----
    {
        const int t = lane, h = wave;
        const float4 qv = *(const float4*)(s_qk + t * 68 + 4 * h);   // pan_q
        const float4 kv = *(const float4*)(s_k2 + t * 36 + 4 * h);   // x_k2
        float qq = qv.x * qv.x + qv.y * qv.y + qv.z * qv.z + qv.w * qv.w;
        float kk = kv.x * kv.x + kv.y * kv.y + kv.z * kv.z + kv.w * kv.w;
        float qk = qv.x * kv.x + qv.y * kv.y + qv.z * kv.z + qv.w * kv.w;
        float cosv = qk * rsqrtf(qq * kk);
        const float4* vp = (const float4*)(s_v1 + t * 68 + 8 * h);   // x_v2
        float4* op = (float4*)(s_cat + t * 68 + 8 * h);              // out2
        float4 v0 = vp[0], v1 = vp[1];
        float4 r0, r1;
        r0.x = cosv * v0.x; r0.y = cosv * v0.y; r0.z = cosv * v0.z; r0.w = cosv * v0.w;
        r1.x = cosv * v1.x; r1.y = cosv * v1.y; r1.z = cosv * v1.z; r1.w = cosv * v1.w;
        op[0] = r0; op[1] = r1;
    }
    __syncthreads();

    // ---- S9: final = out2 @ Wint^T -> s_v1 (8 half-strip tasks) ----
    {
        AF<2> f = load_afrag<64, 68>(s_cat, (wave >> 1) * 16, lane);
        mm<64, 68, 2>(f, wb + OWINT, wlo + OWINT, s_v1,
                      (wave >> 1) * 16, (wave & 1) * 32, lane);
    }
    __syncthreads();

    // ---- store: LDS transpose -> coalesced fp32 float4 stores.
    // thread = (row hl=wave, channel c=lane); LDS read banks (4*wl+c)%32: 2-way.
    {
        const int c = lane, hl = wave;
        float* op = out + (size_t)b * CHW + (size_t)c * HWsz
                        + (size_t)(h0 + hl) * WWD + w0;
        float v[8];
#pragma unroll
        for (int wl = 0; wl < 8; ++wl)
            v[wl] = s_v1[(hl * 8 + wl) * 68 + c];
        float4 q0; q0.x = v[0]; q0.y = v[1]; q0.z = v[2]; q0.w = v[3];
        float4 q1; q1.x = v[4]; q1.y = v[5]; q1.z = v[6]; q1.w = v[7];
        float4* q = (float4*)op;
        q[0] = q0; q[1] = q1;
    }
}

extern "C" void kernel_launch(void* const* d_in, const int* in_sizes, int n_in,
                              void* d_out, int out_size, void* d_ws, size_t ws_size,
                              hipStream_t stream) {
    (void)in_sizes; (void)n_in; (void)out_size; (void)ws_size;
    const float* x    = (const float*)d_in[0];
    const float* pan  = (const float*)d_in[1];
    const float* posi = (const float*)d_in[11];
    const float* posc = (const float*)d_in[12];
    unsigned short* wb = (unsigned short*)d_ws;  // 2*WTOT*2 = 98304 B of ws

    cvt_w<<<WTOT / 256, 256, 0, stream>>>(
        (const float*)d_in[2], (const float*)d_in[3], (const float*)d_in[4],
        (const float*)d_in[5], (const float*)d_in[6], (const float*)d_in[7],
        (const float*)d_in[8], (const float*)d_in[9], (const float*)d_in[10], wb);

    in2ma_main<<<4096, 512, 0, stream>>>(x, pan, posi, posc, wb, (float*)d_out);
}